// Round 16
// baseline (36678.378 us; speedup 1.0000x reference)
//
#include <hip/hip_runtime.h>
#include <cstdint>
#include <cstddef>

#define T_LEN 2048
#define BATCH 128

__device__ __forceinline__ float bcast(float v, int l) {
  return __uint_as_float(__builtin_amdgcn_readlane(__float_as_uint(v), (unsigned)l));
}
__device__ __forceinline__ float sigm(float x) {
  return __builtin_amdgcn_rcpf(1.0f + exp2f(-1.4426950408889634f * x));
}
__device__ __forceinline__ float tanh_fast(float x) {
  return 1.0f - 2.0f * __builtin_amdgcn_rcpf(1.0f + exp2f(2.8853900817779268f * x));
}

// lgkm-only fence + raw barrier: LDS writes visible across waves; global loads
// and h-stores stay in flight across the barrier.
#define BAR()                                              \
  do {                                                     \
    asm volatile("s_waitcnt lgkmcnt(0)" ::: "memory");     \
    __builtin_amdgcn_s_barrier();                          \
    asm volatile("" ::: "memory");                         \
  } while (0)

// ---------------- proj: in0[t*B+b, j] = relu(x[b,t,:] . w_proj[j,:] + b_proj[j])
__global__ __launch_bounds__(256) void proj_kernel(
    const float* __restrict__ x, const float* __restrict__ w_proj,
    const float* __restrict__ b_proj, float* __restrict__ in0) {
  int R = blockIdx.x * 4 + (threadIdx.x >> 6);  // R = t*BATCH + b
  int j = threadIdx.x & 63;
  int t = R >> 7;
  int b = R & 127;
  const float* xr = x + ((size_t)b * T_LEN + t) * 32;
  const float* wr = w_proj + j * 32;
  float a = b_proj[j];
#pragma unroll
  for (int k = 0; k < 32; ++k) a = fmaf(xr[k], wr[k], a);
  in0[(size_t)R * 64 + j] = fmaxf(a, 0.f);
}

// ================= QUAD-SPLIT FUSED LSTM LAYER (R15, best) =================
template <int DIN>
__global__ __attribute__((amdgpu_flat_work_group_size(512, 512),
                          amdgpu_waves_per_eu(2, 2)))
void lstm_quad(const float* __restrict__ in,    // [T*B][DIN]
               float* __restrict__ out,         // [T*B][128]
               const float* __restrict__ w_ih,  // [2,256,DIN]
               const float* __restrict__ w_hh,  // [2,256,64]
               const float* __restrict__ bias)  // [2,256]
{
  constexpr int Q = DIN / 4;          // producer K-quarter width (32 / 16)
  constexpr int NF4C = 8 * DIN / 4;   // float4s per 8-step x chunk (256 / 128)

  const int tid = threadIdx.x;
  const int dir = blockIdx.x & 1;
  const int b = blockIdx.x >> 1;
  const int wv = tid >> 6;   // wave 0..7
  const int qw = wv & 3;     // quarter id (both roles)
  const int l = tid & 63;

  __shared__ float xc[4][8][DIN];    // x chunk ring (4 bufs x 8 steps)
  __shared__ float pre[16][4][256];  // pre partial quarters, 16-step ring
  __shared__ float zq[2][4][256];    // recurrent partial quarters, dbuf

  // cooperative load of chunks 0,1
  {
    int idx = tid;
    if (idx < 2 * NF4C) {
      int ch = idx / NF4C, r = idx % NF4C;
      int sl = r / (DIN / 4), col = r % (DIN / 4);
      int sg = ch * 8 + sl;
      long t = dir ? (T_LEN - 1 - sg) : sg;
      *(float4*)&xc[ch][sl][col * 4] =
          *(const float4*)(in + ((size_t)t * BATCH + b) * DIN + col * 4);
    }
  }
  __syncthreads();

  if (wv >= 4) {
    // ================= producer (waves 4..7) =================
    float4 wr[4 * (Q / 4)];  // 4 gate rows x Q cols
#pragma unroll
    for (int m = 0; m < 4; ++m) {
      const float4* p =
          (const float4*)(w_ih + (size_t)(dir * 256 + m * 64 + l) * DIN + Q * qw);
#pragma unroll
      for (int k = 0; k < Q / 4; ++k) wr[m * (Q / 4) + k] = p[k];
    }
    const float* wf = (const float*)wr;
    const int rlb = __builtin_amdgcn_readfirstlane((Q * qw) & 63);
    const bool hi = (Q * qw) >= 64;
    const int ptid = tid - 256;  // 0..255
    const int xoff = (hi ? 64 : 0) + l;

    // prologue: pre for steps 0..7 from chunk 0
#pragma unroll 1
    for (int j = 0; j < 8; ++j) {
      float xv = xc[0][j][xoff];
      float a0 = 0.f, a1 = 0.f, a2 = 0.f, a3 = 0.f;
#pragma unroll
      for (int kk = 0; kk < Q; ++kk) {
        float xs = bcast(xv, rlb + kk);
        a0 = fmaf(xs, wf[0 * Q + kk], a0);
        a1 = fmaf(xs, wf[1 * Q + kk], a1);
        a2 = fmaf(xs, wf[2 * Q + kk], a2);
        a3 = fmaf(xs, wf[3 * Q + kk], a3);
      }
      pre[j][qw][l] = a0;
      pre[j][qw][64 + l] = a1;
      pre[j][qw][128 + l] = a2;
      pre[j][qw][192 + l] = a3;
    }
    __syncthreads();

    float4 stg;
    const int scol = (ptid % (DIN / 4)) * 4;
    const int srow = ptid / (DIN / 4);
#pragma unroll 1
    for (int i = 0; i <= T_LEN; ++i) {
      // refill ISSUE: chunk c at i%8==0 (x for steps 8c..8c+7)
      if ((i & 7) == 0) {
        int c = (i >> 3) + 2;
        if (8 * c < T_LEN && ptid < NF4C) {
          int sg = c * 8 + srow;
          long t = dir ? (T_LEN - 1 - sg) : sg;
          stg = *(const float4*)(in + ((size_t)t * BATCH + b) * DIN + scol);
        }
      }
      int j = i + 8;  // step whose pre we compute
      if (j < T_LEN) {
        float xv = xc[(j >> 3) & 3][j & 7][xoff];
        float a0 = 0.f, a1 = 0.f, a2 = 0.f, a3 = 0.f;
#pragma unroll
        for (int kk = 0; kk < Q; ++kk) {
          float xs = bcast(xv, rlb + kk);
          a0 = fmaf(xs, wf[0 * Q + kk], a0);
          a1 = fmaf(xs, wf[1 * Q + kk], a1);
          a2 = fmaf(xs, wf[2 * Q + kk], a2);
          a3 = fmaf(xs, wf[3 * Q + kk], a3);
        }
        pre[j & 15][qw][l] = a0;
        pre[j & 15][qw][64 + l] = a1;
        pre[j & 15][qw][128 + l] = a2;
        pre[j & 15][qw][192 + l] = a3;
      }
      // refill WRITE: 4 iterations after issue (~load latency covered)
      if ((i & 7) == 4) {
        int c = (i >> 3) + 2;
        if (8 * c < T_LEN && ptid < NF4C)
          *(float4*)&xc[c & 3][srow][scol] = stg;
      }
      BAR();
    }
  } else {
    // ================= consumer (waves 0..3) =================
    float4 wr[16];  // 4 gate rows x 16 k (quarter [16qw,16qw+16))
#pragma unroll
    for (int m = 0; m < 4; ++m) {
      const float4* p =
          (const float4*)(w_hh + (size_t)(dir * 256 + m * 64 + l) * 64 + 16 * qw);
#pragma unroll
      for (int k = 0; k < 4; ++k) wr[m * 4 + k] = p[k];
    }
    const float* wf = (const float*)wr;
    float bz0 = 0.f, bz1 = 0.f, bz2 = 0.f, bz3 = 0.f;
    if (qw == 0) {  // bias folded once (quarter 0's partial)
      bz0 = bias[dir * 256 + l];
      bz1 = bias[dir * 256 + 64 + l];
      bz2 = bias[dir * 256 + 128 + l];
      bz3 = bias[dir * 256 + 192 + l];
    }
    const int rlb = __builtin_amdgcn_readfirstlane(16 * qw);

    float* outp =
        out + ((size_t)(dir ? (T_LEN - 1) : 0) * BATCH + b) * 128 + dir * 64 + l;
    const ptrdiff_t ostride =
        dir ? -(ptrdiff_t)(BATCH * 128) : (ptrdiff_t)(BATCH * 128);

    __syncthreads();  // matches producer prologue sync

    float h = 0.f, c = 0.f;
#pragma unroll 1
    for (int i = 0; i <= T_LEN; ++i) {
      // pre quarter for step i (h-independent; issued at iteration top)
      float pq0, pq1, pq2, pq3;
      if (i < T_LEN) {
        const float* pp = &pre[i & 15][qw][0];
        pq0 = pp[l];
        pq1 = pp[64 + l];
        pq2 = pp[128 + l];
        pq3 = pp[192 + l];
      }
      if (i > 0) {
        // z of step i-1 = sum of 4 quarters; gates redundant in all 4 waves
        const float* zp = &zq[(i - 1) & 1][0][0];
        float zi = (zp[l] + zp[256 + l]) + (zp[512 + l] + zp[768 + l]);
        float zf = (zp[64 + l] + zp[320 + l]) + (zp[576 + l] + zp[832 + l]);
        float zg = (zp[128 + l] + zp[384 + l]) + (zp[640 + l] + zp[896 + l]);
        float zo = (zp[192 + l] + zp[448 + l]) + (zp[704 + l] + zp[960 + l]);
        float ig = sigm(zi), fg = sigm(zf), gg = tanh_fast(zg), og = sigm(zo);
        c = fmaf(fg, c, ig * gg);
        h = og * tanh_fast(c);
        if (wv == 0) {  // store h_{i-1}; stays in flight across barriers
          *outp = h;
          outp += ostride;
        }
      }
      if (i < T_LEN) {
        // recurrent quarter-dot for step i: 16 RL + 64 FMA
        float a0 = bz0 + pq0, a1 = bz1 + pq1, a2 = bz2 + pq2, a3 = bz3 + pq3;
#pragma unroll
        for (int kk = 0; kk < 16; ++kk) {
          float s = bcast(h, rlb + kk);
          a0 = fmaf(s, wf[kk], a0);
          a1 = fmaf(s, wf[16 + kk], a1);
          a2 = fmaf(s, wf[32 + kk], a2);
          a3 = fmaf(s, wf[48 + kk], a3);
        }
        float* zw = &zq[i & 1][qw][0];
        zw[l] = a0;
        zw[64 + l] = a1;
        zw[128 + l] = a2;
        zw[192 + l] = a3;
      }
      BAR();
    }
  }
}

// ================= DIAG: broadcast-primitive A/B (single wave each) =========
// diag_gate: gates-only serial chain (irreducible floor).
// diag_rl:   64 readlane + 256 FMA + gates (the RL-broadcast dot).
// diag_uni:  16 uniform ds_read_b128 + 256 FMA + gates (LDS-broadcast dot).
// Anti-fold: accumulators use rotated weight indices (distinct weights).
// Sink ring-wraps at 1024 steps: 256 blocks x 256 KB = 64 MB << ws.
template <int STEPS>
__global__ __launch_bounds__(64, 1) void diag_gate(
    const float* __restrict__ w, float* __restrict__ sink) {
  const int l = threadIdx.x;
  float h = 0.001f * w[l], c = 0.f;
  const float k0 = 0.02f * w[64 + l], k1 = 0.02f * w[128 + l];
  const float k2 = 0.02f * w[192 + l], k3 = 0.02f * w[256 + l];
  float* outp = sink + (size_t)blockIdx.x * 65536 + l;
  int wrap = 0;
#pragma unroll 1
  for (int t = 0; t < STEPS; ++t) {
    float a0 = fmaf(h, k0, 0.1f);
    float a1 = fmaf(h, k1, 0.2f);
    float a2 = fmaf(h, k2, -0.1f);
    float a3 = fmaf(h, k3, 0.05f);
    float ig = sigm(a0), fg = sigm(a1), gg = tanh_fast(a2), og = sigm(a3);
    c = fmaf(fg, c, ig * gg);
    h = og * tanh_fast(c);
    *outp = h;
    outp += 64;
    if (++wrap == 1024) { wrap = 0; outp -= 65536; }
  }
}

template <int STEPS>
__global__ __launch_bounds__(64, 1) void diag_rl(
    const float* __restrict__ w_hh, float* __restrict__ sink) {
  const int l = threadIdx.x;
  float wf[64];
  {
    const float* p = w_hh + (size_t)l * 64;
#pragma unroll
    for (int k = 0; k < 64; ++k) wf[k] = p[k];
  }
  float h = 0.001f * w_hh[l], c = 0.f;
  float* outp = sink + (size_t)blockIdx.x * 65536 + l;
  int wrap = 0;
#pragma unroll 1
  for (int t = 0; t < STEPS; ++t) {
    float a0 = 0.1f, a1 = 0.2f, a2 = -0.1f, a3 = 0.05f;
#pragma unroll
    for (int k = 0; k < 64; ++k) {
      float s = bcast(h, k);
      a0 = fmaf(s, wf[k], a0);
      a1 = fmaf(s, wf[(k + 1) & 63], a1);
      a2 = fmaf(s, wf[(k + 2) & 63], a2);
      a3 = fmaf(s, wf[(k + 3) & 63], a3);
    }
    float ig = sigm(a0), fg = sigm(a1), gg = tanh_fast(a2), og = sigm(a3);
    c = fmaf(fg, c, ig * gg);
    h = og * tanh_fast(c);
    *outp = h;
    outp += 64;
    if (++wrap == 1024) { wrap = 0; outp -= 65536; }
  }
}

template <int STEPS>
__global__ __launch_bounds__(64, 1) void diag_uni(
    const float* __restrict__ w_hh, float* __restrict__ sink) {
  const int l = threadIdx.x;
  __shared__ float hb[64];
  float wf[64];
  {
    const float* p = w_hh + (size_t)l * 64;
#pragma unroll
    for (int k = 0; k < 64; ++k) wf[k] = p[k];
  }
  float h = 0.001f * w_hh[l], c = 0.f;
  hb[l] = h;
  float* outp = sink + (size_t)blockIdx.x * 65536 + l;
  int wrap = 0;
#pragma unroll 1
  for (int t = 0; t < STEPS; ++t) {
    float4 h4[16];
#pragma unroll
    for (int q = 0; q < 16; ++q) h4[q] = *(const float4*)&hb[4 * q];  // uniform
    const float* hs = (const float*)h4;
    float a0 = 0.1f, a1 = 0.2f, a2 = -0.1f, a3 = 0.05f;
#pragma unroll
    for (int k = 0; k < 64; ++k) {
      float s = hs[k];
      a0 = fmaf(s, wf[k], a0);
      a1 = fmaf(s, wf[(k + 1) & 63], a1);
      a2 = fmaf(s, wf[(k + 2) & 63], a2);
      a3 = fmaf(s, wf[(k + 3) & 63], a3);
    }
    float ig = sigm(a0), fg = sigm(a1), gg = tanh_fast(a2), og = sigm(a3);
    c = fmaf(fg, c, ig * gg);
    h = og * tanh_fast(c);
    hb[l] = h;  // same-wave DS order: next iter's uniform reads see it
    *outp = h;
    outp += 64;
    if (++wrap == 1024) { wrap = 0; outp -= 65536; }
  }
}

// ---------------- attention: scores + softmax + pooled, one block per batch row
__global__ __launch_bounds__(256) void attn_kernel(
    const float* __restrict__ hs, const float* __restrict__ w_attn,
    float* __restrict__ pooled) {
  const int b = blockIdx.x, tid = threadIdx.x;
  __shared__ float wa[128];
  __shared__ float sc[T_LEN];
  __shared__ float red[256];
  if (tid < 128) wa[tid] = w_attn[tid];
  __syncthreads();

  float lmax = -3.4e38f;
#pragma unroll
  for (int i = 0; i < T_LEN / 256; ++i) {
    int t = tid + 256 * i;
    const float4* r4 = (const float4*)(hs + ((size_t)t * BATCH + b) * 128);
    float s = 0.f;
#pragma unroll
    for (int k = 0; k < 32; ++k) {
      float4 v = r4[k];
      s += v.x * wa[4 * k] + v.y * wa[4 * k + 1] + v.z * wa[4 * k + 2] + v.w * wa[4 * k + 3];
    }
    sc[t] = s;
    lmax = fmaxf(lmax, s);
  }
  red[tid] = lmax;
  __syncthreads();
  for (int off = 128; off > 0; off >>= 1) {
    if (tid < off) red[tid] = fmaxf(red[tid], red[tid + off]);
    __syncthreads();
  }
  float m = red[0];
  __syncthreads();

  float lsum = 0.f;
#pragma unroll
  for (int i = 0; i < T_LEN / 256; ++i) {
    int t = tid + 256 * i;
    float e = exp2f((sc[t] - m) * 1.4426950408889634f);
    sc[t] = e;
    lsum += e;
  }
  red[tid] = lsum;
  __syncthreads();
  for (int off = 128; off > 0; off >>= 1) {
    if (tid < off) red[tid] += red[tid + off];
    __syncthreads();
  }
  float inv = __builtin_amdgcn_rcpf(red[0]);

  if (tid < 128) {
    float a0 = 0.f, a1 = 0.f, a2 = 0.f, a3 = 0.f;
    for (int t = 0; t < T_LEN; t += 4) {
      a0 = fmaf(sc[t], hs[((size_t)t * BATCH + b) * 128 + tid], a0);
      a1 = fmaf(sc[t + 1], hs[((size_t)(t + 1) * BATCH + b) * 128 + tid], a1);
      a2 = fmaf(sc[t + 2], hs[((size_t)(t + 2) * BATCH + b) * 128 + tid], a2);
      a3 = fmaf(sc[t + 3], hs[((size_t)(t + 3) * BATCH + b) * 128 + tid], a3);
    }
    pooled[b * 128 + tid] = ((a0 + a1) + (a2 + a3)) * inv;
  }
}

// ---------------- head: BN1 -> fc1 -> relu -> fc2 -> elu -> BN2 -> fc3
__global__ __launch_bounds__(128) void head_kernel(
    const float* __restrict__ pooled,
    const float* g1, const float* be1, const float* m1, const float* v1,
    const float* w1, const float* b1, const float* w2, const float* b2,
    const float* g2, const float* be2, const float* m2, const float* v2,
    const float* w3, const float* b3, float* __restrict__ out) {
  const int b = blockIdx.x, tid = threadIdx.x;
  __shared__ float xb[128], y1[128], y2[64];
  xb[tid] = (pooled[b * 128 + tid] - m1[tid]) * rsqrtf(v1[tid] + 1e-5f) * g1[tid] + be1[tid];
  __syncthreads();
  float a = b1[tid];
#pragma unroll 8
  for (int k = 0; k < 128; ++k) a = fmaf(xb[k], w1[tid * 128 + k], a);
  y1[tid] = fmaxf(a, 0.f);
  __syncthreads();
  if (tid < 64) {
    float a2 = b2[tid];
#pragma unroll 8
    for (int k = 0; k < 128; ++k) a2 = fmaf(y1[k], w2[tid * 128 + k], a2);
    if (a2 < 0.f) a2 = exp2f(a2 * 1.4426950408889634f) - 1.0f;  // elu
    y2[tid] = (a2 - m2[tid]) * rsqrtf(v2[tid] + 1e-5f) * g2[tid] + be2[tid];
  }
  __syncthreads();
  if (tid < 3) {
    float a3 = b3[tid];
#pragma unroll
    for (int k = 0; k < 64; ++k) a3 = fmaf(y2[k], w3[tid * 64 + k], a3);
    out[b * 3 + tid] = a3;
  }
}

extern "C" void kernel_launch(void* const* d_in, const int* in_sizes, int n_in,
                              void* d_out, int out_size, void* d_ws, size_t ws_size,
                              hipStream_t stream) {
  const float* x      = (const float*)d_in[0];
  const float* w_proj = (const float*)d_in[1];
  const float* b_proj = (const float*)d_in[2];
  const float* w_ih_l0 = (const float*)d_in[3];
  const float* w_hh_l0 = (const float*)d_in[4];
  const float* b_l0    = (const float*)d_in[5];
  const float* w_ih_r  = (const float*)d_in[6];  // [3,2,256,128]
  const float* w_hh_r  = (const float*)d_in[7];  // [3,2,256,64]
  const float* b_r     = (const float*)d_in[8];  // [3,2,256]
  const float* w_attn  = (const float*)d_in[9];
  const float* g1  = (const float*)d_in[11];
  const float* be1 = (const float*)d_in[12];
  const float* m1  = (const float*)d_in[13];
  const float* v1  = (const float*)d_in[14];
  const float* w1  = (const float*)d_in[15];
  const float* b1  = (const float*)d_in[16];
  const float* w2  = (const float*)d_in[17];
  const float* b2  = (const float*)d_in[18];
  const float* g2  = (const float*)d_in[19];
  const float* be2 = (const float*)d_in[20];
  const float* m2  = (const float*)d_in[21];
  const float* v2  = (const float*)d_in[22];
  const float* w3  = (const float*)d_in[23];
  const float* b3  = (const float*)d_in[24];
  float* out = (float*)d_out;

  // ws layout: bufA [T,B,128] | bufB [T,B,128]  (in0 and pooled overlay dead regions)
  const size_t BUF_FLOATS = (size_t)T_LEN * BATCH * 128;
  float* bufA = (float*)d_ws;
  float* bufB = bufA + BUF_FLOATS;
  float* in0 = bufB;     // [T,B,64]; dead once layer1 writes bufB
  float* pooled = bufA;  // dead region after last layer reads bufA

  proj_kernel<<<T_LEN * BATCH / 4, 256, 0, stream>>>(x, w_proj, b_proj, in0);
  lstm_quad<64><<<256, 512, 0, stream>>>(in0, bufA, w_ih_l0, w_hh_l0, b_l0);
  lstm_quad<128><<<256, 512, 0, stream>>>(bufA, bufB, w_ih_r, w_hh_r, b_r);
  lstm_quad<128><<<256, 512, 0, stream>>>(bufB, bufA, w_ih_r + 65536, w_hh_r + 32768, b_r + 512);
  lstm_quad<128><<<256, 512, 0, stream>>>(bufA, bufB, w_ih_r + 131072, w_hh_r + 65536, b_r + 1024);
  attn_kernel<<<BATCH, 256, 0, stream>>>(bufB, w_attn, pooled);
  head_kernel<<<BATCH, 128, 0, stream>>>(pooled, g1, be1, m1, v1, w1, b1, w2, b2,
                                         g2, be2, m2, v2, w3, b3, out);

  // ---- diagnostics (after head; bounded 64 MB sink in dead ws region)
  diag_gate<65536><<<256, 64, 0, stream>>>(w_hh_l0, (float*)d_ws);
  diag_rl<8192><<<256, 64, 0, stream>>>(w_hh_l0, (float*)d_ws);
  diag_uni<16384><<<256, 64, 0, stream>>>(w_hh_l0, (float*)d_ws);
}

// Round 17
// 5152.729 us; speedup vs baseline: 7.1182x; 7.1182x over previous
//
#include <hip/hip_runtime.h>
#include <cstdint>
#include <cstddef>

#define T_LEN 2048
#define BATCH 128

__device__ __forceinline__ float sigm(float x) {
  return __builtin_amdgcn_rcpf(1.0f + exp2f(-1.4426950408889634f * x));
}
__device__ __forceinline__ float tanh_fast(float x) {
  return 1.0f - 2.0f * __builtin_amdgcn_rcpf(1.0f + exp2f(2.8853900817779268f * x));
}

// lgkm-only fence + raw barrier: LDS writes visible across waves; global loads
// and h-stores stay in flight across the barrier.
#define BAR()                                              \
  do {                                                     \
    asm volatile("s_waitcnt lgkmcnt(0)" ::: "memory");     \
    __builtin_amdgcn_s_barrier();                          \
    asm volatile("" ::: "memory");                         \
  } while (0)

// ---------------- proj: in0[t*B+b, j] = relu(x[b,t,:] . w_proj[j,:] + b_proj[j])
__global__ __launch_bounds__(256) void proj_kernel(
    const float* __restrict__ x, const float* __restrict__ w_proj,
    const float* __restrict__ b_proj, float* __restrict__ in0) {
  int R = blockIdx.x * 4 + (threadIdx.x >> 6);  // R = t*BATCH + b
  int j = threadIdx.x & 63;
  int t = R >> 7;
  int b = R & 127;
  const float* xr = x + ((size_t)b * T_LEN + t) * 32;
  const float* wr = w_proj + j * 32;
  float a = b_proj[j];
#pragma unroll
  for (int k = 0; k < 32; ++k) a = fmaf(xr[k], wr[k], a);
  in0[(size_t)R * 64 + j] = fmaxf(a, 0.f);
}

// ================= QUAD-SPLIT FUSED LSTM LAYER (R15 minus readlane) =========
// Block = (b, dir), 512 threads = 8 waves, waves_per_eu(2,2).
// R17 change (single variable vs R15): ALL broadcasts via same-wave uniform
// LDS reads instead of v_readlane (R14/R15 evidence: ~2.5x instruction bloat
// common to every RL variant; gates+stores measured <473 cy/step).
// Consumers w0-3: write h to a private hcb row, read the 16-value quarter
//   back as 4 uniform ds_read_b128 (program-ordered, no barrier).
// Producers w4-7: read their x K-slice directly from xc as uniform b128.
template <int DIN>
__global__ __attribute__((amdgpu_flat_work_group_size(512, 512),
                          amdgpu_waves_per_eu(2, 2)))
void lstm_quad(const float* __restrict__ in,    // [T*B][DIN]
               float* __restrict__ out,         // [T*B][128]
               const float* __restrict__ w_ih,  // [2,256,DIN]
               const float* __restrict__ w_hh,  // [2,256,64]
               const float* __restrict__ bias)  // [2,256]
{
  constexpr int Q = DIN / 4;          // producer K-quarter width (32 / 16)
  constexpr int NF4C = 8 * DIN / 4;   // float4s per 8-step x chunk (256 / 128)

  const int tid = threadIdx.x;
  const int dir = blockIdx.x & 1;
  const int b = blockIdx.x >> 1;
  const int wv = tid >> 6;   // wave 0..7
  const int qw = wv & 3;     // quarter id (both roles)
  const int l = tid & 63;

  __shared__ float xc[4][8][DIN];    // x chunk ring (4 bufs x 8 steps)
  __shared__ float pre[16][4][256];  // pre partial quarters, 16-step ring
  __shared__ float zq[2][4][256];    // recurrent partial quarters, dbuf
  __shared__ float hcb[4][64];       // per-consumer-wave private h copy

  // cooperative load of chunks 0,1
  {
    int idx = tid;
    if (idx < 2 * NF4C) {
      int ch = idx / NF4C, r = idx % NF4C;
      int sl = r / (DIN / 4), col = r % (DIN / 4);
      int sg = ch * 8 + sl;
      long t = dir ? (T_LEN - 1 - sg) : sg;
      *(float4*)&xc[ch][sl][col * 4] =
          *(const float4*)(in + ((size_t)t * BATCH + b) * DIN + col * 4);
    }
  }
  __syncthreads();

  if (wv >= 4) {
    // ================= producer (waves 4..7) =================
    float4 wr[4 * (Q / 4)];  // 4 gate rows x Q cols
#pragma unroll
    for (int m = 0; m < 4; ++m) {
      const float4* p =
          (const float4*)(w_ih + (size_t)(dir * 256 + m * 64 + l) * DIN + Q * qw);
#pragma unroll
      for (int k = 0; k < Q / 4; ++k) wr[m * (Q / 4) + k] = p[k];
    }
    const float* wf = (const float*)wr;
    const int ptid = tid - 256;  // 0..255

    // prologue: pre for steps 0..7 from chunk 0
#pragma unroll 1
    for (int j = 0; j < 8; ++j) {
      float4 xv[Q / 4];
      const float* xrow = &xc[0][j][Q * qw];
#pragma unroll
      for (int q2 = 0; q2 < Q / 4; ++q2)
        xv[q2] = *(const float4*)&xrow[4 * q2];  // uniform b128 broadcast
      const float* xs = (const float*)xv;
      float a0 = 0.f, a1 = 0.f, a2 = 0.f, a3 = 0.f;
#pragma unroll
      for (int kk = 0; kk < Q; ++kk) {
        float s = xs[kk];
        a0 = fmaf(s, wf[0 * Q + kk], a0);
        a1 = fmaf(s, wf[1 * Q + kk], a1);
        a2 = fmaf(s, wf[2 * Q + kk], a2);
        a3 = fmaf(s, wf[3 * Q + kk], a3);
      }
      pre[j][qw][l] = a0;
      pre[j][qw][64 + l] = a1;
      pre[j][qw][128 + l] = a2;
      pre[j][qw][192 + l] = a3;
    }
    __syncthreads();

    float4 stg;
    const int scol = (ptid % (DIN / 4)) * 4;
    const int srow = ptid / (DIN / 4);
#pragma unroll 1
    for (int i = 0; i <= T_LEN; ++i) {
      // refill ISSUE: chunk c at i%8==0 (x for steps 8c..8c+7)
      if ((i & 7) == 0) {
        int c = (i >> 3) + 2;
        if (8 * c < T_LEN && ptid < NF4C) {
          int sg = c * 8 + srow;
          long t = dir ? (T_LEN - 1 - sg) : sg;
          stg = *(const float4*)(in + ((size_t)t * BATCH + b) * DIN + scol);
        }
      }
      int j = i + 8;  // step whose pre we compute
      if (j < T_LEN) {
        float4 xv[Q / 4];
        const float* xrow = &xc[(j >> 3) & 3][j & 7][Q * qw];
#pragma unroll
        for (int q2 = 0; q2 < Q / 4; ++q2)
          xv[q2] = *(const float4*)&xrow[4 * q2];  // uniform b128 broadcast
        const float* xs = (const float*)xv;
        float a0 = 0.f, a1 = 0.f, a2 = 0.f, a3 = 0.f;
#pragma unroll
        for (int kk = 0; kk < Q; ++kk) {
          float s = xs[kk];
          a0 = fmaf(s, wf[0 * Q + kk], a0);
          a1 = fmaf(s, wf[1 * Q + kk], a1);
          a2 = fmaf(s, wf[2 * Q + kk], a2);
          a3 = fmaf(s, wf[3 * Q + kk], a3);
        }
        pre[j & 15][qw][l] = a0;
        pre[j & 15][qw][64 + l] = a1;
        pre[j & 15][qw][128 + l] = a2;
        pre[j & 15][qw][192 + l] = a3;
      }
      // refill WRITE: 4 iterations after issue (~load latency covered)
      if ((i & 7) == 4) {
        int c = (i >> 3) + 2;
        if (8 * c < T_LEN && ptid < NF4C)
          *(float4*)&xc[c & 3][srow][scol] = stg;
      }
      BAR();
    }
  } else {
    // ================= consumer (waves 0..3) =================
    float4 wr[16];  // 4 gate rows x 16 k (quarter [16qw,16qw+16))
#pragma unroll
    for (int m = 0; m < 4; ++m) {
      const float4* p =
          (const float4*)(w_hh + (size_t)(dir * 256 + m * 64 + l) * 64 + 16 * qw);
#pragma unroll
      for (int k = 0; k < 4; ++k) wr[m * 4 + k] = p[k];
    }
    const float* wf = (const float*)wr;
    float bz0 = 0.f, bz1 = 0.f, bz2 = 0.f, bz3 = 0.f;
    if (qw == 0) {  // bias folded once (quarter 0's partial)
      bz0 = bias[dir * 256 + l];
      bz1 = bias[dir * 256 + 64 + l];
      bz2 = bias[dir * 256 + 128 + l];
      bz3 = bias[dir * 256 + 192 + l];
    }

    float* outp =
        out + ((size_t)(dir ? (T_LEN - 1) : 0) * BATCH + b) * 128 + dir * 64 + l;
    const ptrdiff_t ostride =
        dir ? -(ptrdiff_t)(BATCH * 128) : (ptrdiff_t)(BATCH * 128);

    hcb[qw][l] = 0.f;  // h_0 = 0 (own wave's private row; program-ordered)
    __syncthreads();   // matches producer prologue sync

    float h = 0.f, c = 0.f;
#pragma unroll 1
    for (int i = 0; i <= T_LEN; ++i) {
      // pre quarter for step i (h-independent; issued at iteration top)
      float pq0, pq1, pq2, pq3;
      if (i < T_LEN) {
        const float* pp = &pre[i & 15][qw][0];
        pq0 = pp[l];
        pq1 = pp[64 + l];
        pq2 = pp[128 + l];
        pq3 = pp[192 + l];
      }
      if (i > 0) {
        // z of step i-1 = sum of 4 quarters; gates redundant in all 4 waves
        const float* zp = &zq[(i - 1) & 1][0][0];
        float zi = (zp[l] + zp[256 + l]) + (zp[512 + l] + zp[768 + l]);
        float zf = (zp[64 + l] + zp[320 + l]) + (zp[576 + l] + zp[832 + l]);
        float zg = (zp[128 + l] + zp[384 + l]) + (zp[640 + l] + zp[896 + l]);
        float zo = (zp[192 + l] + zp[448 + l]) + (zp[704 + l] + zp[960 + l]);
        float ig = sigm(zi), fg = sigm(zf), gg = tanh_fast(zg), og = sigm(zo);
        c = fmaf(fg, c, ig * gg);
        h = og * tanh_fast(c);
        hcb[qw][l] = h;  // own-wave private copy; next reads program-ordered
        if (wv == 0) {   // store h_{i-1}; stays in flight across barriers
          *outp = h;
          outp += ostride;
        }
      }
      if (i < T_LEN) {
        // recurrent quarter-dot: 4 uniform b128 h-reads + 64 FMA (no readlane)
        float4 hq[4];
        const float* hrow = &hcb[qw][16 * qw];
#pragma unroll
        for (int q2 = 0; q2 < 4; ++q2)
          hq[q2] = *(const float4*)&hrow[4 * q2];  // uniform b128 broadcast
        const float* hs = (const float*)hq;
        float a0 = bz0 + pq0, a1 = bz1 + pq1, a2 = bz2 + pq2, a3 = bz3 + pq3;
#pragma unroll
        for (int kk = 0; kk < 16; ++kk) {
          float s = hs[kk];
          a0 = fmaf(s, wf[kk], a0);
          a1 = fmaf(s, wf[16 + kk], a1);
          a2 = fmaf(s, wf[32 + kk], a2);
          a3 = fmaf(s, wf[48 + kk], a3);
        }
        float* zw = &zq[i & 1][qw][0];
        zw[l] = a0;
        zw[64 + l] = a1;
        zw[128 + l] = a2;
        zw[192 + l] = a3;
      }
      BAR();
    }
  }
}

// ---------------- attention: scores + softmax + pooled, one block per batch row
__global__ __launch_bounds__(256) void attn_kernel(
    const float* __restrict__ hs, const float* __restrict__ w_attn,
    float* __restrict__ pooled) {
  const int b = blockIdx.x, tid = threadIdx.x;
  __shared__ float wa[128];
  __shared__ float sc[T_LEN];
  __shared__ float red[256];
  if (tid < 128) wa[tid] = w_attn[tid];
  __syncthreads();

  float lmax = -3.4e38f;
#pragma unroll
  for (int i = 0; i < T_LEN / 256; ++i) {
    int t = tid + 256 * i;
    const float4* r4 = (const float4*)(hs + ((size_t)t * BATCH + b) * 128);
    float s = 0.f;
#pragma unroll
    for (int k = 0; k < 32; ++k) {
      float4 v = r4[k];
      s += v.x * wa[4 * k] + v.y * wa[4 * k + 1] + v.z * wa[4 * k + 2] + v.w * wa[4 * k + 3];
    }
    sc[t] = s;
    lmax = fmaxf(lmax, s);
  }
  red[tid] = lmax;
  __syncthreads();
  for (int off = 128; off > 0; off >>= 1) {
    if (tid < off) red[tid] = fmaxf(red[tid], red[tid + off]);
    __syncthreads();
  }
  float m = red[0];
  __syncthreads();

  float lsum = 0.f;
#pragma unroll
  for (int i = 0; i < T_LEN / 256; ++i) {
    int t = tid + 256 * i;
    float e = exp2f((sc[t] - m) * 1.4426950408889634f);
    sc[t] = e;
    lsum += e;
  }
  red[tid] = lsum;
  __syncthreads();
  for (int off = 128; off > 0; off >>= 1) {
    if (tid < off) red[tid] += red[tid + off];
    __syncthreads();
  }
  float inv = __builtin_amdgcn_rcpf(red[0]);

  if (tid < 128) {
    float a0 = 0.f, a1 = 0.f, a2 = 0.f, a3 = 0.f;
    for (int t = 0; t < T_LEN; t += 4) {
      a0 = fmaf(sc[t], hs[((size_t)t * BATCH + b) * 128 + tid], a0);
      a1 = fmaf(sc[t + 1], hs[((size_t)(t + 1) * BATCH + b) * 128 + tid], a1);
      a2 = fmaf(sc[t + 2], hs[((size_t)(t + 2) * BATCH + b) * 128 + tid], a2);
      a3 = fmaf(sc[t + 3], hs[((size_t)(t + 3) * BATCH + b) * 128 + tid], a3);
    }
    pooled[b * 128 + tid] = ((a0 + a1) + (a2 + a3)) * inv;
  }
}

// ---------------- head: BN1 -> fc1 -> relu -> fc2 -> elu -> BN2 -> fc3
__global__ __launch_bounds__(128) void head_kernel(
    const float* __restrict__ pooled,
    const float* g1, const float* be1, const float* m1, const float* v1,
    const float* w1, const float* b1, const float* w2, const float* b2,
    const float* g2, const float* be2, const float* m2, const float* v2,
    const float* w3, const float* b3, float* __restrict__ out) {
  const int b = blockIdx.x, tid = threadIdx.x;
  __shared__ float xb[128], y1[128], y2[64];
  xb[tid] = (pooled[b * 128 + tid] - m1[tid]) * rsqrtf(v1[tid] + 1e-5f) * g1[tid] + be1[tid];
  __syncthreads();
  float a = b1[tid];
#pragma unroll 8
  for (int k = 0; k < 128; ++k) a = fmaf(xb[k], w1[tid * 128 + k], a);
  y1[tid] = fmaxf(a, 0.f);
  __syncthreads();
  if (tid < 64) {
    float a2 = b2[tid];
#pragma unroll 8
    for (int k = 0; k < 128; ++k) a2 = fmaf(y1[k], w2[tid * 128 + k], a2);
    if (a2 < 0.f) a2 = exp2f(a2 * 1.4426950408889634f) - 1.0f;  // elu
    y2[tid] = (a2 - m2[tid]) * rsqrtf(v2[tid] + 1e-5f) * g2[tid] + be2[tid];
  }
  __syncthreads();
  if (tid < 3) {
    float a3 = b3[tid];
#pragma unroll
    for (int k = 0; k < 64; ++k) a3 = fmaf(y2[k], w3[tid * 64 + k], a3);
    out[b * 3 + tid] = a3;
  }
}

extern "C" void kernel_launch(void* const* d_in, const int* in_sizes, int n_in,
                              void* d_out, int out_size, void* d_ws, size_t ws_size,
                              hipStream_t stream) {
  const float* x      = (const float*)d_in[0];
  const float* w_proj = (const float*)d_in[1];
  const float* b_proj = (const float*)d_in[2];
  const float* w_ih_l0 = (const float*)d_in[3];
  const float* w_hh_l0 = (const float*)d_in[4];
  const float* b_l0    = (const float*)d_in[5];
  const float* w_ih_r  = (const float*)d_in[6];  // [3,2,256,128]
  const float* w_hh_r  = (const float*)d_in[7];  // [3,2,256,64]
  const float* b_r     = (const float*)d_in[8];  // [3,2,256]
  const float* w_attn  = (const float*)d_in[9];
  const float* g1  = (const float*)d_in[11];
  const float* be1 = (const float*)d_in[12];
  const float* m1  = (const float*)d_in[13];
  const float* v1  = (const float*)d_in[14];
  const float* w1  = (const float*)d_in[15];
  const float* b1  = (const float*)d_in[16];
  const float* w2  = (const float*)d_in[17];
  const float* b2  = (const float*)d_in[18];
  const float* g2  = (const float*)d_in[19];
  const float* be2 = (const float*)d_in[20];
  const float* m2  = (const float*)d_in[21];
  const float* v2  = (const float*)d_in[22];
  const float* w3  = (const float*)d_in[23];
  const float* b3  = (const float*)d_in[24];
  float* out = (float*)d_out;

  // ws layout: bufA [T,B,128] | bufB [T,B,128]  (in0 and pooled overlay dead regions)
  const size_t BUF_FLOATS = (size_t)T_LEN * BATCH * 128;
  float* bufA = (float*)d_ws;
  float* bufB = bufA + BUF_FLOATS;
  float* in0 = bufB;     // [T,B,64]; dead once layer1 writes bufB
  float* pooled = bufA;  // dead region after last layer reads bufA

  proj_kernel<<<T_LEN * BATCH / 4, 256, 0, stream>>>(x, w_proj, b_proj, in0);
  lstm_quad<64><<<256, 512, 0, stream>>>(in0, bufA, w_ih_l0, w_hh_l0, b_l0);
  lstm_quad<128><<<256, 512, 0, stream>>>(bufA, bufB, w_ih_r, w_hh_r, b_r);
  lstm_quad<128><<<256, 512, 0, stream>>>(bufB, bufA, w_ih_r + 65536, w_hh_r + 32768, b_r + 512);
  lstm_quad<128><<<256, 512, 0, stream>>>(bufA, bufB, w_ih_r + 131072, w_hh_r + 65536, b_r + 1024);
  attn_kernel<<<BATCH, 256, 0, stream>>>(bufB, w_attn, pooled);
  head_kernel<<<BATCH, 128, 0, stream>>>(pooled, g1, be1, m1, v1, w1, b1, w2, b2,
                                         g2, be2, m2, v2, w3, b3, out);
}

// Round 18
// 4336.208 us; speedup vs baseline: 8.4586x; 1.1883x over previous
//
#include <hip/hip_runtime.h>
#include <cstdint>
#include <cstddef>

#define T_LEN 2048
#define BATCH 128

__device__ __forceinline__ float sigm(float x) {
  return __builtin_amdgcn_rcpf(1.0f + exp2f(-1.4426950408889634f * x));
}
__device__ __forceinline__ float tanh_fast(float x) {
  return 1.0f - 2.0f * __builtin_amdgcn_rcpf(1.0f + exp2f(2.8853900817779268f * x));
}

// lgkm-only fence + raw barrier: LDS writes visible across waves; global loads
// and h-stores stay in flight across the barrier.
#define BAR()                                              \
  do {                                                     \
    asm volatile("s_waitcnt lgkmcnt(0)" ::: "memory");     \
    __builtin_amdgcn_s_barrier();                          \
    asm volatile("" ::: "memory");                         \
  } while (0)

// ---------------- proj: in0[t*B+b, j] = relu(x[b,t,:] . w_proj[j,:] + b_proj[j])
__global__ __launch_bounds__(256) void proj_kernel(
    const float* __restrict__ x, const float* __restrict__ w_proj,
    const float* __restrict__ b_proj, float* __restrict__ in0) {
  int R = blockIdx.x * 4 + (threadIdx.x >> 6);  // R = t*BATCH + b
  int j = threadIdx.x & 63;
  int t = R >> 7;
  int b = R & 127;
  const float* xr = x + ((size_t)b * T_LEN + t) * 32;
  const float* wr = w_proj + j * 32;
  float a = b_proj[j];
#pragma unroll
  for (int k = 0; k < 32; ++k) a = fmaf(xr[k], wr[k], a);
  in0[(size_t)R * 64 + j] = fmaxf(a, 0.f);
}

// ================= QUAD-SPLIT FUSED LSTM LAYER (R17 + static rings) =========
// Block = (b, dir), 512 threads = 8 waves, waves_per_eu(2,2).
// R18 change (vs R17): pre ring 16->8 slots, producer LEAD 8->4, and
// #pragma unroll 8 on both role loops so all ring indices/parities/guards
// fold to compile-time constants (R17 counters: VALUBusy 83%, ~2x inst bloat
// vs useful work = dynamic-loop addressing tax).
// Race audit (LEAD=4, ring 8): slot s for step j written at iter j-4, read
// at iter j, rewritten (step j+8) at iter j+4 -> all >=4 barriers apart.
template <int DIN>
__global__ __attribute__((amdgpu_flat_work_group_size(512, 512),
                          amdgpu_waves_per_eu(2, 2)))
void lstm_quad(const float* __restrict__ in,    // [T*B][DIN]
               float* __restrict__ out,         // [T*B][128]
               const float* __restrict__ w_ih,  // [2,256,DIN]
               const float* __restrict__ w_hh,  // [2,256,64]
               const float* __restrict__ bias)  // [2,256]
{
  constexpr int Q = DIN / 4;          // producer K-quarter width (32 / 16)
  constexpr int NF4C = 8 * DIN / 4;   // float4s per 8-step x chunk (256 / 128)

  const int tid = threadIdx.x;
  const int dir = blockIdx.x & 1;
  const int b = blockIdx.x >> 1;
  const int wv = tid >> 6;   // wave 0..7
  const int qw = wv & 3;     // quarter id (both roles)
  const int l = tid & 63;

  __shared__ float xc[4][8][DIN];    // x chunk ring (4 bufs x 8 steps)
  __shared__ float pre[8][4][256];   // pre partial quarters, 8-step ring
  __shared__ float zq[2][4][256];    // recurrent partial quarters, dbuf
  __shared__ float hcb[4][64];       // per-consumer-wave private h copy

  // cooperative load of chunks 0,1
  {
    int idx = tid;
    if (idx < 2 * NF4C) {
      int ch = idx / NF4C, r = idx % NF4C;
      int sl = r / (DIN / 4), col = r % (DIN / 4);
      int sg = ch * 8 + sl;
      long t = dir ? (T_LEN - 1 - sg) : sg;
      *(float4*)&xc[ch][sl][col * 4] =
          *(const float4*)(in + ((size_t)t * BATCH + b) * DIN + col * 4);
    }
  }
  __syncthreads();

  if (wv >= 4) {
    // ================= producer (waves 4..7) =================
    float4 wr[4 * (Q / 4)];  // 4 gate rows x Q cols
#pragma unroll
    for (int m = 0; m < 4; ++m) {
      const float4* p =
          (const float4*)(w_ih + (size_t)(dir * 256 + m * 64 + l) * DIN + Q * qw);
#pragma unroll
      for (int k = 0; k < Q / 4; ++k) wr[m * (Q / 4) + k] = p[k];
    }
    const float* wf = (const float*)wr;
    const int ptid = tid - 256;  // 0..255

    // prologue: pre for steps 0..3 (LEAD=4) from chunk 0
#pragma unroll
    for (int j = 0; j < 4; ++j) {
      float4 xv[Q / 4];
      const float* xrow = &xc[0][j][Q * qw];
#pragma unroll
      for (int q2 = 0; q2 < Q / 4; ++q2)
        xv[q2] = *(const float4*)&xrow[4 * q2];  // uniform b128 broadcast
      const float* xs = (const float*)xv;
      float a0 = 0.f, a1 = 0.f, a2 = 0.f, a3 = 0.f;
#pragma unroll
      for (int kk = 0; kk < Q; ++kk) {
        float s = xs[kk];
        a0 = fmaf(s, wf[0 * Q + kk], a0);
        a1 = fmaf(s, wf[1 * Q + kk], a1);
        a2 = fmaf(s, wf[2 * Q + kk], a2);
        a3 = fmaf(s, wf[3 * Q + kk], a3);
      }
      pre[j][qw][l] = a0;
      pre[j][qw][64 + l] = a1;
      pre[j][qw][128 + l] = a2;
      pre[j][qw][192 + l] = a3;
    }
    __syncthreads();

    float4 stg;
    const int scol = (ptid % (DIN / 4)) * 4;
    const int srow = ptid / (DIN / 4);
#pragma unroll 8
    for (int i = 0; i <= T_LEN; ++i) {
      // refill ISSUE: chunk c at i%8==0 (x for steps 8c..8c+7)
      if ((i & 7) == 0) {
        int c = (i >> 3) + 2;
        if (8 * c < T_LEN && ptid < NF4C) {
          int sg = c * 8 + srow;
          long t = dir ? (T_LEN - 1 - sg) : sg;
          stg = *(const float4*)(in + ((size_t)t * BATCH + b) * DIN + scol);
        }
      }
      int j = i + 4;  // step whose pre we compute (LEAD=4)
      if (j < T_LEN) {
        float4 xv[Q / 4];
        const float* xrow = &xc[(j >> 3) & 3][j & 7][Q * qw];
#pragma unroll
        for (int q2 = 0; q2 < Q / 4; ++q2)
          xv[q2] = *(const float4*)&xrow[4 * q2];  // uniform b128 broadcast
        const float* xs = (const float*)xv;
        float a0 = 0.f, a1 = 0.f, a2 = 0.f, a3 = 0.f;
#pragma unroll
        for (int kk = 0; kk < Q; ++kk) {
          float s = xs[kk];
          a0 = fmaf(s, wf[0 * Q + kk], a0);
          a1 = fmaf(s, wf[1 * Q + kk], a1);
          a2 = fmaf(s, wf[2 * Q + kk], a2);
          a3 = fmaf(s, wf[3 * Q + kk], a3);
        }
        pre[j & 7][qw][l] = a0;
        pre[j & 7][qw][64 + l] = a1;
        pre[j & 7][qw][128 + l] = a2;
        pre[j & 7][qw][192 + l] = a3;
      }
      // refill WRITE: 4 iterations after issue (~load latency covered)
      if ((i & 7) == 4) {
        int c = (i >> 3) + 2;
        if (8 * c < T_LEN && ptid < NF4C)
          *(float4*)&xc[c & 3][srow][scol] = stg;
      }
      BAR();
    }
  } else {
    // ================= consumer (waves 0..3) =================
    float4 wr[16];  // 4 gate rows x 16 k (quarter [16qw,16qw+16))
#pragma unroll
    for (int m = 0; m < 4; ++m) {
      const float4* p =
          (const float4*)(w_hh + (size_t)(dir * 256 + m * 64 + l) * 64 + 16 * qw);
#pragma unroll
      for (int k = 0; k < 4; ++k) wr[m * 4 + k] = p[k];
    }
    const float* wf = (const float*)wr;
    float bz0 = 0.f, bz1 = 0.f, bz2 = 0.f, bz3 = 0.f;
    if (qw == 0) {  // bias folded once (quarter 0's partial)
      bz0 = bias[dir * 256 + l];
      bz1 = bias[dir * 256 + 64 + l];
      bz2 = bias[dir * 256 + 128 + l];
      bz3 = bias[dir * 256 + 192 + l];
    }

    float* outp =
        out + ((size_t)(dir ? (T_LEN - 1) : 0) * BATCH + b) * 128 + dir * 64 + l;
    const ptrdiff_t ostride =
        dir ? -(ptrdiff_t)(BATCH * 128) : (ptrdiff_t)(BATCH * 128);

    hcb[qw][l] = 0.f;  // h_0 = 0 (own wave's private row; program-ordered)
    __syncthreads();   // matches producer prologue sync

    float h = 0.f, c = 0.f;
#pragma unroll 8
    for (int i = 0; i <= T_LEN; ++i) {
      // pre quarter for step i (h-independent; issued at iteration top)
      float pq0, pq1, pq2, pq3;
      if (i < T_LEN) {
        const float* pp = &pre[i & 7][qw][0];
        pq0 = pp[l];
        pq1 = pp[64 + l];
        pq2 = pp[128 + l];
        pq3 = pp[192 + l];
      }
      if (i > 0) {
        // z of step i-1 = sum of 4 quarters; gates redundant in all 4 waves
        const float* zp = &zq[(i - 1) & 1][0][0];
        float zi = (zp[l] + zp[256 + l]) + (zp[512 + l] + zp[768 + l]);
        float zf = (zp[64 + l] + zp[320 + l]) + (zp[576 + l] + zp[832 + l]);
        float zg = (zp[128 + l] + zp[384 + l]) + (zp[640 + l] + zp[896 + l]);
        float zo = (zp[192 + l] + zp[448 + l]) + (zp[704 + l] + zp[960 + l]);
        float ig = sigm(zi), fg = sigm(zf), gg = tanh_fast(zg), og = sigm(zo);
        c = fmaf(fg, c, ig * gg);
        h = og * tanh_fast(c);
        hcb[qw][l] = h;  // own-wave private copy; next reads program-ordered
        if (wv == 0) {   // store h_{i-1}; stays in flight across barriers
          *outp = h;
          outp += ostride;
        }
      }
      if (i < T_LEN) {
        // recurrent quarter-dot: 4 uniform b128 h-reads + 64 FMA (no readlane)
        float4 hq[4];
        const float* hrow = &hcb[qw][16 * qw];
#pragma unroll
        for (int q2 = 0; q2 < 4; ++q2)
          hq[q2] = *(const float4*)&hrow[4 * q2];  // uniform b128 broadcast
        const float* hs = (const float*)hq;
        float a0 = bz0 + pq0, a1 = bz1 + pq1, a2 = bz2 + pq2, a3 = bz3 + pq3;
#pragma unroll
        for (int kk = 0; kk < 16; ++kk) {
          float s = hs[kk];
          a0 = fmaf(s, wf[kk], a0);
          a1 = fmaf(s, wf[16 + kk], a1);
          a2 = fmaf(s, wf[32 + kk], a2);
          a3 = fmaf(s, wf[48 + kk], a3);
        }
        float* zw = &zq[i & 1][qw][0];
        zw[l] = a0;
        zw[64 + l] = a1;
        zw[128 + l] = a2;
        zw[192 + l] = a3;
      }
      BAR();
    }
  }
}

// ---------------- attention: scores + softmax + pooled, one block per batch row
__global__ __launch_bounds__(256) void attn_kernel(
    const float* __restrict__ hs, const float* __restrict__ w_attn,
    float* __restrict__ pooled) {
  const int b = blockIdx.x, tid = threadIdx.x;
  __shared__ float wa[128];
  __shared__ float sc[T_LEN];
  __shared__ float red[256];
  if (tid < 128) wa[tid] = w_attn[tid];
  __syncthreads();

  float lmax = -3.4e38f;
#pragma unroll
  for (int i = 0; i < T_LEN / 256; ++i) {
    int t = tid + 256 * i;
    const float4* r4 = (const float4*)(hs + ((size_t)t * BATCH + b) * 128);
    float s = 0.f;
#pragma unroll
    for (int k = 0; k < 32; ++k) {
      float4 v = r4[k];
      s += v.x * wa[4 * k] + v.y * wa[4 * k + 1] + v.z * wa[4 * k + 2] + v.w * wa[4 * k + 3];
    }
    sc[t] = s;
    lmax = fmaxf(lmax, s);
  }
  red[tid] = lmax;
  __syncthreads();
  for (int off = 128; off > 0; off >>= 1) {
    if (tid < off) red[tid] = fmaxf(red[tid], red[tid + off]);
    __syncthreads();
  }
  float m = red[0];
  __syncthreads();

  float lsum = 0.f;
#pragma unroll
  for (int i = 0; i < T_LEN / 256; ++i) {
    int t = tid + 256 * i;
    float e = exp2f((sc[t] - m) * 1.4426950408889634f);
    sc[t] = e;
    lsum += e;
  }
  red[tid] = lsum;
  __syncthreads();
  for (int off = 128; off > 0; off >>= 1) {
    if (tid < off) red[tid] += red[tid + off];
    __syncthreads();
  }
  float inv = __builtin_amdgcn_rcpf(red[0]);

  if (tid < 128) {
    float a0 = 0.f, a1 = 0.f, a2 = 0.f, a3 = 0.f;
    for (int t = 0; t < T_LEN; t += 4) {
      a0 = fmaf(sc[t], hs[((size_t)t * BATCH + b) * 128 + tid], a0);
      a1 = fmaf(sc[t + 1], hs[((size_t)(t + 1) * BATCH + b) * 128 + tid], a1);
      a2 = fmaf(sc[t + 2], hs[((size_t)(t + 2) * BATCH + b) * 128 + tid], a2);
      a3 = fmaf(sc[t + 3], hs[((size_t)(t + 3) * BATCH + b) * 128 + tid], a3);
    }
    pooled[b * 128 + tid] = ((a0 + a1) + (a2 + a3)) * inv;
  }
}

// ---------------- head: BN1 -> fc1 -> relu -> fc2 -> elu -> BN2 -> fc3
__global__ __launch_bounds__(128) void head_kernel(
    const float* __restrict__ pooled,
    const float* g1, const float* be1, const float* m1, const float* v1,
    const float* w1, const float* b1, const float* w2, const float* b2,
    const float* g2, const float* be2, const float* m2, const float* v2,
    const float* w3, const float* b3, float* __restrict__ out) {
  const int b = blockIdx.x, tid = threadIdx.x;
  __shared__ float xb[128], y1[128], y2[64];
  xb[tid] = (pooled[b * 128 + tid] - m1[tid]) * rsqrtf(v1[tid] + 1e-5f) * g1[tid] + be1[tid];
  __syncthreads();
  float a = b1[tid];
#pragma unroll 8
  for (int k = 0; k < 128; ++k) a = fmaf(xb[k], w1[tid * 128 + k], a);
  y1[tid] = fmaxf(a, 0.f);
  __syncthreads();
  if (tid < 64) {
    float a2 = b2[tid];
#pragma unroll 8
    for (int k = 0; k < 128; ++k) a2 = fmaf(y1[k], w2[tid * 128 + k], a2);
    if (a2 < 0.f) a2 = exp2f(a2 * 1.4426950408889634f) - 1.0f;  // elu
    y2[tid] = (a2 - m2[tid]) * rsqrtf(v2[tid] + 1e-5f) * g2[tid] + be2[tid];
  }
  __syncthreads();
  if (tid < 3) {
    float a3 = b3[tid];
#pragma unroll
    for (int k = 0; k < 64; ++k) a3 = fmaf(y2[k], w3[tid * 64 + k], a3);
    out[b * 3 + tid] = a3;
  }
}

extern "C" void kernel_launch(void* const* d_in, const int* in_sizes, int n_in,
                              void* d_out, int out_size, void* d_ws, size_t ws_size,
                              hipStream_t stream) {
  const float* x      = (const float*)d_in[0];
  const float* w_proj = (const float*)d_in[1];
  const float* b_proj = (const float*)d_in[2];
  const float* w_ih_l0 = (const float*)d_in[3];
  const float* w_hh_l0 = (const float*)d_in[4];
  const float* b_l0    = (const float*)d_in[5];
  const float* w_ih_r  = (const float*)d_in[6];  // [3,2,256,128]
  const float* w_hh_r  = (const float*)d_in[7];  // [3,2,256,64]
  const float* b_r     = (const float*)d_in[8];  // [3,2,256]
  const float* w_attn  = (const float*)d_in[9];
  const float* g1  = (const float*)d_in[11];
  const float* be1 = (const float*)d_in[12];
  const float* m1  = (const float*)d_in[13];
  const float* v1  = (const float*)d_in[14];
  const float* w1  = (const float*)d_in[15];
  const float* b1  = (const float*)d_in[16];
  const float* w2  = (const float*)d_in[17];
  const float* b2  = (const float*)d_in[18];
  const float* g2  = (const float*)d_in[19];
  const float* be2 = (const float*)d_in[20];
  const float* m2  = (const float*)d_in[21];
  const float* v2  = (const float*)d_in[22];
  const float* w3  = (const float*)d_in[23];
  const float* b3  = (const float*)d_in[24];
  float* out = (float*)d_out;

  // ws layout: bufA [T,B,128] | bufB [T,B,128]  (in0 and pooled overlay dead regions)
  const size_t BUF_FLOATS = (size_t)T_LEN * BATCH * 128;
  float* bufA = (float*)d_ws;
  float* bufB = bufA + BUF_FLOATS;
  float* in0 = bufB;     // [T,B,64]; dead once layer1 writes bufB
  float* pooled = bufA;  // dead region after last layer reads bufA

  proj_kernel<<<T_LEN * BATCH / 4, 256, 0, stream>>>(x, w_proj, b_proj, in0);
  lstm_quad<64><<<256, 512, 0, stream>>>(in0, bufA, w_ih_l0, w_hh_l0, b_l0);
  lstm_quad<128><<<256, 512, 0, stream>>>(bufA, bufB, w_ih_r, w_hh_r, b_r);
  lstm_quad<128><<<256, 512, 0, stream>>>(bufB, bufA, w_ih_r + 65536, w_hh_r + 32768, b_r + 512);
  lstm_quad<128><<<256, 512, 0, stream>>>(bufA, bufB, w_ih_r + 131072, w_hh_r + 65536, b_r + 1024);
  attn_kernel<<<BATCH, 256, 0, stream>>>(bufB, w_attn, pooled);
  head_kernel<<<BATCH, 128, 0, stream>>>(pooled, g1, be1, m1, v1, w1, b1, w2, b2,
                                         g2, be2, m2, v2, w3, b3, out);
}

// Round 19
// 4300.994 us; speedup vs baseline: 8.5279x; 1.0082x over previous
//
#include <hip/hip_runtime.h>
#include <cstdint>
#include <cstddef>

#define T_LEN 2048
#define BATCH 128

typedef float v2f __attribute__((ext_vector_type(2)));

__device__ __forceinline__ float sigm(float x) {
  return __builtin_amdgcn_rcpf(1.0f + exp2f(-1.4426950408889634f * x));
}
__device__ __forceinline__ float tanh_fast(float x) {
  return 1.0f - 2.0f * __builtin_amdgcn_rcpf(1.0f + exp2f(2.8853900817779268f * x));
}

// lgkm-only fence + raw barrier: LDS writes visible across waves; global loads
// and h-stores stay in flight across the barrier.
#define BAR()                                              \
  do {                                                     \
    asm volatile("s_waitcnt lgkmcnt(0)" ::: "memory");     \
    __builtin_amdgcn_s_barrier();                          \
    asm volatile("" ::: "memory");                         \
  } while (0)

// ---------------- proj: in0[t*B+b, j] = relu(x[b,t,:] . w_proj[j,:] + b_proj[j])
__global__ __launch_bounds__(256) void proj_kernel(
    const float* __restrict__ x, const float* __restrict__ w_proj,
    const float* __restrict__ b_proj, float* __restrict__ in0) {
  int R = blockIdx.x * 4 + (threadIdx.x >> 6);  // R = t*BATCH + b
  int j = threadIdx.x & 63;
  int t = R >> 7;
  int b = R & 127;
  const float* xr = x + ((size_t)b * T_LEN + t) * 32;
  const float* wr = w_proj + j * 32;
  float a = b_proj[j];
#pragma unroll
  for (int k = 0; k < 32; ++k) a = fmaf(xr[k], wr[k], a);
  in0[(size_t)R * 64 + j] = fmaxf(a, 0.f);
}

// ================= QUAD-SPLIT FUSED LSTM LAYER (R18 + pk-FMA along k) =======
// Block = (b, dir), 512 threads = 8 waves, waves_per_eu(2,2).
// R19 change (single variable vs R18): dot products use v_pk_fma_f32 packed
// ALONG K — h/x pairs {v[2k],v[2k+1]} come free from the b128 uniform reads,
// weight pairs are adjacent in the float4 register loads -> no mov overhead,
// 1 horizontal add per accumulator. Halves FMA issue (R18: VALUBusy 90%,
// issue-bound; regime now correct for pk per rule-23, unlike R11's null).
template <int DIN>
__global__ __attribute__((amdgpu_flat_work_group_size(512, 512),
                          amdgpu_waves_per_eu(2, 2)))
void lstm_quad(const float* __restrict__ in,    // [T*B][DIN]
               float* __restrict__ out,         // [T*B][128]
               const float* __restrict__ w_ih,  // [2,256,DIN]
               const float* __restrict__ w_hh,  // [2,256,64]
               const float* __restrict__ bias)  // [2,256]
{
  constexpr int Q = DIN / 4;          // producer K-quarter width (32 / 16)
  constexpr int NF4C = 8 * DIN / 4;   // float4s per 8-step x chunk (256 / 128)

  const int tid = threadIdx.x;
  const int dir = blockIdx.x & 1;
  const int b = blockIdx.x >> 1;
  const int wv = tid >> 6;   // wave 0..7
  const int qw = wv & 3;     // quarter id (both roles)
  const int l = tid & 63;

  __shared__ float xc[4][8][DIN];    // x chunk ring (4 bufs x 8 steps)
  __shared__ float pre[8][4][256];   // pre partial quarters, 8-step ring
  __shared__ float zq[2][4][256];    // recurrent partial quarters, dbuf
  __shared__ float hcb[4][64];       // per-consumer-wave private h copy

  // cooperative load of chunks 0,1
  {
    int idx = tid;
    if (idx < 2 * NF4C) {
      int ch = idx / NF4C, r = idx % NF4C;
      int sl = r / (DIN / 4), col = r % (DIN / 4);
      int sg = ch * 8 + sl;
      long t = dir ? (T_LEN - 1 - sg) : sg;
      *(float4*)&xc[ch][sl][col * 4] =
          *(const float4*)(in + ((size_t)t * BATCH + b) * DIN + col * 4);
    }
  }
  __syncthreads();

  if (wv >= 4) {
    // ================= producer (waves 4..7) =================
    float4 wr[4 * (Q / 4)];  // 4 gate rows x Q cols
#pragma unroll
    for (int m = 0; m < 4; ++m) {
      const float4* p =
          (const float4*)(w_ih + (size_t)(dir * 256 + m * 64 + l) * DIN + Q * qw);
#pragma unroll
      for (int k = 0; k < Q / 4; ++k) wr[m * (Q / 4) + k] = p[k];
    }
    const v2f* wf2 = (const v2f*)wr;  // [4][Q/2] k-pairs
    const int ptid = tid - 256;       // 0..255

    // prologue: pre for steps 0..3 (LEAD=4) from chunk 0
#pragma unroll
    for (int j = 0; j < 4; ++j) {
      float4 xv[Q / 4];
      const float* xrow = &xc[0][j][Q * qw];
#pragma unroll
      for (int q2 = 0; q2 < Q / 4; ++q2)
        xv[q2] = *(const float4*)&xrow[4 * q2];  // uniform b128 broadcast
      const v2f* xp = (const v2f*)xv;
      v2f a0 = (v2f){0.f, 0.f}, a1 = (v2f){0.f, 0.f};
      v2f a2 = (v2f){0.f, 0.f}, a3 = (v2f){0.f, 0.f};
#pragma unroll
      for (int p = 0; p < Q / 2; ++p) {
        v2f xs2 = xp[p];
        a0 = __builtin_elementwise_fma(xs2, wf2[0 * (Q / 2) + p], a0);
        a1 = __builtin_elementwise_fma(xs2, wf2[1 * (Q / 2) + p], a1);
        a2 = __builtin_elementwise_fma(xs2, wf2[2 * (Q / 2) + p], a2);
        a3 = __builtin_elementwise_fma(xs2, wf2[3 * (Q / 2) + p], a3);
      }
      pre[j][qw][l] = a0.x + a0.y;
      pre[j][qw][64 + l] = a1.x + a1.y;
      pre[j][qw][128 + l] = a2.x + a2.y;
      pre[j][qw][192 + l] = a3.x + a3.y;
    }
    __syncthreads();

    float4 stg;
    const int scol = (ptid % (DIN / 4)) * 4;
    const int srow = ptid / (DIN / 4);
#pragma unroll 8
    for (int i = 0; i <= T_LEN; ++i) {
      // refill ISSUE: chunk c at i%8==0 (x for steps 8c..8c+7)
      if ((i & 7) == 0) {
        int c = (i >> 3) + 2;
        if (8 * c < T_LEN && ptid < NF4C) {
          int sg = c * 8 + srow;
          long t = dir ? (T_LEN - 1 - sg) : sg;
          stg = *(const float4*)(in + ((size_t)t * BATCH + b) * DIN + scol);
        }
      }
      int j = i + 4;  // step whose pre we compute (LEAD=4)
      if (j < T_LEN) {
        float4 xv[Q / 4];
        const float* xrow = &xc[(j >> 3) & 3][j & 7][Q * qw];
#pragma unroll
        for (int q2 = 0; q2 < Q / 4; ++q2)
          xv[q2] = *(const float4*)&xrow[4 * q2];  // uniform b128 broadcast
        const v2f* xp = (const v2f*)xv;
        v2f a0 = (v2f){0.f, 0.f}, a1 = (v2f){0.f, 0.f};
        v2f a2 = (v2f){0.f, 0.f}, a3 = (v2f){0.f, 0.f};
#pragma unroll
        for (int p = 0; p < Q / 2; ++p) {
          v2f xs2 = xp[p];
          a0 = __builtin_elementwise_fma(xs2, wf2[0 * (Q / 2) + p], a0);
          a1 = __builtin_elementwise_fma(xs2, wf2[1 * (Q / 2) + p], a1);
          a2 = __builtin_elementwise_fma(xs2, wf2[2 * (Q / 2) + p], a2);
          a3 = __builtin_elementwise_fma(xs2, wf2[3 * (Q / 2) + p], a3);
        }
        pre[j & 7][qw][l] = a0.x + a0.y;
        pre[j & 7][qw][64 + l] = a1.x + a1.y;
        pre[j & 7][qw][128 + l] = a2.x + a2.y;
        pre[j & 7][qw][192 + l] = a3.x + a3.y;
      }
      // refill WRITE: 4 iterations after issue (~load latency covered)
      if ((i & 7) == 4) {
        int c = (i >> 3) + 2;
        if (8 * c < T_LEN && ptid < NF4C)
          *(float4*)&xc[c & 3][srow][scol] = stg;
      }
      BAR();
    }
  } else {
    // ================= consumer (waves 0..3) =================
    float4 wr[16];  // 4 gate rows x 16 k (quarter [16qw,16qw+16))
#pragma unroll
    for (int m = 0; m < 4; ++m) {
      const float4* p =
          (const float4*)(w_hh + (size_t)(dir * 256 + m * 64 + l) * 64 + 16 * qw);
#pragma unroll
      for (int k = 0; k < 4; ++k) wr[m * 4 + k] = p[k];
    }
    const v2f* wf2 = (const v2f*)wr;  // [4][8] k-pairs
    float bz0 = 0.f, bz1 = 0.f, bz2 = 0.f, bz3 = 0.f;
    if (qw == 0) {  // bias folded once (quarter 0's partial)
      bz0 = bias[dir * 256 + l];
      bz1 = bias[dir * 256 + 64 + l];
      bz2 = bias[dir * 256 + 128 + l];
      bz3 = bias[dir * 256 + 192 + l];
    }

    float* outp =
        out + ((size_t)(dir ? (T_LEN - 1) : 0) * BATCH + b) * 128 + dir * 64 + l;
    const ptrdiff_t ostride =
        dir ? -(ptrdiff_t)(BATCH * 128) : (ptrdiff_t)(BATCH * 128);

    hcb[qw][l] = 0.f;  // h_0 = 0 (own wave's private row; program-ordered)
    __syncthreads();   // matches producer prologue sync

    float h = 0.f, c = 0.f;
#pragma unroll 8
    for (int i = 0; i <= T_LEN; ++i) {
      // pre quarter for step i (h-independent; issued at iteration top)
      float pq0, pq1, pq2, pq3;
      if (i < T_LEN) {
        const float* pp = &pre[i & 7][qw][0];
        pq0 = pp[l];
        pq1 = pp[64 + l];
        pq2 = pp[128 + l];
        pq3 = pp[192 + l];
      }
      if (i > 0) {
        // z of step i-1 = sum of 4 quarters; gates redundant in all 4 waves
        const float* zp = &zq[(i - 1) & 1][0][0];
        float zi = (zp[l] + zp[256 + l]) + (zp[512 + l] + zp[768 + l]);
        float zf = (zp[64 + l] + zp[320 + l]) + (zp[576 + l] + zp[832 + l]);
        float zg = (zp[128 + l] + zp[384 + l]) + (zp[640 + l] + zp[896 + l]);
        float zo = (zp[192 + l] + zp[448 + l]) + (zp[704 + l] + zp[960 + l]);
        float ig = sigm(zi), fg = sigm(zf), gg = tanh_fast(zg), og = sigm(zo);
        c = fmaf(fg, c, ig * gg);
        h = og * tanh_fast(c);
        hcb[qw][l] = h;  // own-wave private copy; next reads program-ordered
        if (wv == 0) {   // store h_{i-1}; stays in flight across barriers
          *outp = h;
          outp += ostride;
        }
      }
      if (i < T_LEN) {
        // recurrent quarter-dot: 4 uniform b128 h-reads + 32 pk-FMA along k
        float4 hq[4];
        const float* hrow = &hcb[qw][16 * qw];
#pragma unroll
        for (int q2 = 0; q2 < 4; ++q2)
          hq[q2] = *(const float4*)&hrow[4 * q2];  // uniform b128 broadcast
        const v2f* hp = (const v2f*)hq;  // 8 natural k-pairs
        v2f a0 = (v2f){bz0 + pq0, 0.f}, a1 = (v2f){bz1 + pq1, 0.f};
        v2f a2 = (v2f){bz2 + pq2, 0.f}, a3 = (v2f){bz3 + pq3, 0.f};
#pragma unroll
        for (int p = 0; p < 8; ++p) {
          v2f hs2 = hp[p];
          a0 = __builtin_elementwise_fma(hs2, wf2[p], a0);
          a1 = __builtin_elementwise_fma(hs2, wf2[8 + p], a1);
          a2 = __builtin_elementwise_fma(hs2, wf2[16 + p], a2);
          a3 = __builtin_elementwise_fma(hs2, wf2[24 + p], a3);
        }
        float* zw = &zq[i & 1][qw][0];
        zw[l] = a0.x + a0.y;
        zw[64 + l] = a1.x + a1.y;
        zw[128 + l] = a2.x + a2.y;
        zw[192 + l] = a3.x + a3.y;
      }
      BAR();
    }
  }
}

// ---------------- attention: scores + softmax + pooled, one block per batch row
__global__ __launch_bounds__(256) void attn_kernel(
    const float* __restrict__ hs, const float* __restrict__ w_attn,
    float* __restrict__ pooled) {
  const int b = blockIdx.x, tid = threadIdx.x;
  __shared__ float wa[128];
  __shared__ float sc[T_LEN];
  __shared__ float red[256];
  if (tid < 128) wa[tid] = w_attn[tid];
  __syncthreads();

  float lmax = -3.4e38f;
#pragma unroll
  for (int i = 0; i < T_LEN / 256; ++i) {
    int t = tid + 256 * i;
    const float4* r4 = (const float4*)(hs + ((size_t)t * BATCH + b) * 128);
    float s = 0.f;
#pragma unroll
    for (int k = 0; k < 32; ++k) {
      float4 v = r4[k];
      s += v.x * wa[4 * k] + v.y * wa[4 * k + 1] + v.z * wa[4 * k + 2] + v.w * wa[4 * k + 3];
    }
    sc[t] = s;
    lmax = fmaxf(lmax, s);
  }
  red[tid] = lmax;
  __syncthreads();
  for (int off = 128; off > 0; off >>= 1) {
    if (tid < off) red[tid] = fmaxf(red[tid], red[tid + off]);
    __syncthreads();
  }
  float m = red[0];
  __syncthreads();

  float lsum = 0.f;
#pragma unroll
  for (int i = 0; i < T_LEN / 256; ++i) {
    int t = tid + 256 * i;
    float e = exp2f((sc[t] - m) * 1.4426950408889634f);
    sc[t] = e;
    lsum += e;
  }
  red[tid] = lsum;
  __syncthreads();
  for (int off = 128; off > 0; off >>= 1) {
    if (tid < off) red[tid] += red[tid + off];
    __syncthreads();
  }
  float inv = __builtin_amdgcn_rcpf(red[0]);

  if (tid < 128) {
    float a0 = 0.f, a1 = 0.f, a2 = 0.f, a3 = 0.f;
    for (int t = 0; t < T_LEN; t += 4) {
      a0 = fmaf(sc[t], hs[((size_t)t * BATCH + b) * 128 + tid], a0);
      a1 = fmaf(sc[t + 1], hs[((size_t)(t + 1) * BATCH + b) * 128 + tid], a1);
      a2 = fmaf(sc[t + 2], hs[((size_t)(t + 2) * BATCH + b) * 128 + tid], a2);
      a3 = fmaf(sc[t + 3], hs[((size_t)(t + 3) * BATCH + b) * 128 + tid], a3);
    }
    pooled[b * 128 + tid] = ((a0 + a1) + (a2 + a3)) * inv;
  }
}

// ---------------- head: BN1 -> fc1 -> relu -> fc2 -> elu -> BN2 -> fc3
__global__ __launch_bounds__(128) void head_kernel(
    const float* __restrict__ pooled,
    const float* g1, const float* be1, const float* m1, const float* v1,
    const float* w1, const float* b1, const float* w2, const float* b2,
    const float* g2, const float* be2, const float* m2, const float* v2,
    const float* w3, const float* b3, float* __restrict__ out) {
  const int b = blockIdx.x, tid = threadIdx.x;
  __shared__ float xb[128], y1[128], y2[64];
  xb[tid] = (pooled[b * 128 + tid] - m1[tid]) * rsqrtf(v1[tid] + 1e-5f) * g1[tid] + be1[tid];
  __syncthreads();
  float a = b1[tid];
#pragma unroll 8
  for (int k = 0; k < 128; ++k) a = fmaf(xb[k], w1[tid * 128 + k], a);
  y1[tid] = fmaxf(a, 0.f);
  __syncthreads();
  if (tid < 64) {
    float a2 = b2[tid];
#pragma unroll 8
    for (int k = 0; k < 128; ++k) a2 = fmaf(y1[k], w2[tid * 128 + k], a2);
    if (a2 < 0.f) a2 = exp2f(a2 * 1.4426950408889634f) - 1.0f;  // elu
    y2[tid] = (a2 - m2[tid]) * rsqrtf(v2[tid] + 1e-5f) * g2[tid] + be2[tid];
  }
  __syncthreads();
  if (tid < 3) {
    float a3 = b3[tid];
#pragma unroll
    for (int k = 0; k < 64; ++k) a3 = fmaf(y2[k], w3[tid * 64 + k], a3);
    out[b * 3 + tid] = a3;
  }
}

extern "C" void kernel_launch(void* const* d_in, const int* in_sizes, int n_in,
                              void* d_out, int out_size, void* d_ws, size_t ws_size,
                              hipStream_t stream) {
  const float* x      = (const float*)d_in[0];
  const float* w_proj = (const float*)d_in[1];
  const float* b_proj = (const float*)d_in[2];
  const float* w_ih_l0 = (const float*)d_in[3];
  const float* w_hh_l0 = (const float*)d_in[4];
  const float* b_l0    = (const float*)d_in[5];
  const float* w_ih_r  = (const float*)d_in[6];  // [3,2,256,128]
  const float* w_hh_r  = (const float*)d_in[7];  // [3,2,256,64]
  const float* b_r     = (const float*)d_in[8];  // [3,2,256]
  const float* w_attn  = (const float*)d_in[9];
  const float* g1  = (const float*)d_in[11];
  const float* be1 = (const float*)d_in[12];
  const float* m1  = (const float*)d_in[13];
  const float* v1  = (const float*)d_in[14];
  const float* w1  = (const float*)d_in[15];
  const float* b1  = (const float*)d_in[16];
  const float* w2  = (const float*)d_in[17];
  const float* b2  = (const float*)d_in[18];
  const float* g2  = (const float*)d_in[19];
  const float* be2 = (const float*)d_in[20];
  const float* m2  = (const float*)d_in[21];
  const float* v2  = (const float*)d_in[22];
  const float* w3  = (const float*)d_in[23];
  const float* b3  = (const float*)d_in[24];
  float* out = (float*)d_out;

  // ws layout: bufA [T,B,128] | bufB [T,B,128]  (in0 and pooled overlay dead regions)
  const size_t BUF_FLOATS = (size_t)T_LEN * BATCH * 128;
  float* bufA = (float*)d_ws;
  float* bufB = bufA + BUF_FLOATS;
  float* in0 = bufB;     // [T,B,64]; dead once layer1 writes bufB
  float* pooled = bufA;  // dead region after last layer reads bufA

  proj_kernel<<<T_LEN * BATCH / 4, 256, 0, stream>>>(x, w_proj, b_proj, in0);
  lstm_quad<64><<<256, 512, 0, stream>>>(in0, bufA, w_ih_l0, w_hh_l0, b_l0);
  lstm_quad<128><<<256, 512, 0, stream>>>(bufA, bufB, w_ih_r, w_hh_r, b_r);
  lstm_quad<128><<<256, 512, 0, stream>>>(bufB, bufA, w_ih_r + 65536, w_hh_r + 32768, b_r + 512);
  lstm_quad<128><<<256, 512, 0, stream>>>(bufA, bufB, w_ih_r + 131072, w_hh_r + 65536, b_r + 1024);
  attn_kernel<<<BATCH, 256, 0, stream>>>(bufB, w_attn, pooled);
  head_kernel<<<BATCH, 128, 0, stream>>>(pooled, g1, be1, m1, v1, w1, b1, w2, b2,
                                         g2, be2, m2, v2, w3, b3, out);
}